// Round 2
// baseline (162.412 us; speedup 1.0000x reference)
//
#include <hip/hip_runtime.h>
#include <cmath>

#define HDIM 1024
#define LSEQ 2048
#define VOCAB 50257

__device__ __forceinline__ float wave_sum(float v) {
#pragma unroll
    for (int off = 32; off; off >>= 1) v += __shfl_down(v, off, 64);
    return v;
}

__device__ __forceinline__ float wave_max(float v) {
#pragma unroll
    for (int off = 32; off; off >>= 1) v = fmaxf(v, __shfl_down(v, off, 64));
    return v;
}

__device__ __forceinline__ void lse_combine(float& m, float& s, float m2, float s2) {
    float nm = fmaxf(m, m2);
    s = s * expf(m - nm) + s2 * expf(m2 - nm);
    m = nm;
}

// ---------------------------------------------------------------------------
// 1. h = tanh(W_ih @ x + b_ih + W_hh @ h0 + b_hh);  one wave per output row.
//    rows: 0..2047  (d = row>>10, i = row&1023)
//    writes h into concat[d*2048 + 1024 + i] and d_out tail.
__global__ void rnn_kernel(const int* __restrict__ tok,
                           const float* __restrict__ hidden,
                           const float* __restrict__ emb,
                           const float* __restrict__ W_ih,
                           const float* __restrict__ W_hh,
                           const float* __restrict__ b_ih,
                           const float* __restrict__ b_hh,
                           float* __restrict__ concat,
                           float* __restrict__ out_h) {
    int wave = threadIdx.x >> 6, lane = threadIdx.x & 63;
    int row = blockIdx.x * 4 + wave;            // 512 blocks * 4 waves = 2048
    int d = row >> 10, i = row & 1023;
    int t = tok[0];
    const float* x  = emb + (size_t)t * HDIM;
    const float* h0 = hidden + d * HDIM;        // (2,1,H) flat
    const float* wi = W_ih + (size_t)d * HDIM * HDIM + (size_t)i * HDIM;
    const float* wh = W_hh + (size_t)d * HDIM * HDIM + (size_t)i * HDIM;
    float acc = 0.f;
#pragma unroll
    for (int p = 0; p < 4; ++p) {
        int o = p * 256 + lane * 4;
        float4 a = *(const float4*)(wi + o);
        float4 b = *(const float4*)(x + o);
        acc += a.x * b.x + a.y * b.y + a.z * b.z + a.w * b.w;
        float4 c = *(const float4*)(wh + o);
        float4 e = *(const float4*)(h0 + o);
        acc += c.x * e.x + c.y * e.y + c.z * e.z + c.w * e.w;
    }
    acc = wave_sum(acc);
    if (lane == 0) {
        float hv = tanhf(acc + b_ih[d * HDIM + i] + b_hh[d * HDIM + i]);
        concat[d * 2048 + 1024 + i] = hv;
        out_h[d * HDIM + i] = hv;
    }
}

// ---------------------------------------------------------------------------
// 2. energy[d][l] = h[d] . enc[l];  one wave per (d,l).  rows 0..4095
__global__ void energy_kernel(const float* __restrict__ enc,
                              const float* __restrict__ concat,
                              float* __restrict__ energy) {
    int wave = threadIdx.x >> 6, lane = threadIdx.x & 63;
    int row = blockIdx.x * 4 + wave;            // 1024 blocks * 4 waves = 4096
    int d = row >> 11, l = row & 2047;
    const float* h  = concat + d * 2048 + 1024;
    const float* er = enc + (size_t)l * HDIM;
    float acc = 0.f;
#pragma unroll
    for (int p = 0; p < 4; ++p) {
        int o = p * 256 + lane * 4;
        float4 a = *(const float4*)(er + o);
        float4 b = *(const float4*)(h + o);
        acc += a.x * b.x + a.y * b.y + a.z * b.z + a.w * b.w;
    }
    acc = wave_sum(acc);
    if (lane == 0) energy[row] = acc;
}

// ---------------------------------------------------------------------------
// 3. softmax over L per direction. grid=2, block=256, 8 elems/thread.
__global__ void softmax_kernel(const float* __restrict__ energy,
                               float* __restrict__ attnw) {
    __shared__ float red[4];
    int d = blockIdx.x, t = threadIdx.x;
    int lane = t & 63, wave = t >> 6;
    const float* e = energy + d * LSEQ;
    float vals[8];
    float m = -1e30f;
#pragma unroll
    for (int k = 0; k < 8; ++k) { vals[k] = e[t + 256 * k]; m = fmaxf(m, vals[k]); }
    m = wave_max(m);
    if (lane == 0) red[wave] = m;
    __syncthreads();
    m = fmaxf(fmaxf(red[0], red[1]), fmaxf(red[2], red[3]));
    __syncthreads();
    float s = 0.f;
#pragma unroll
    for (int k = 0; k < 8; ++k) { vals[k] = expf(vals[k] - m); s += vals[k]; }
    s = wave_sum(s);
    if (lane == 0) red[wave] = s;
    __syncthreads();
    s = red[0] + red[1] + red[2] + red[3];
    float inv = 1.f / s;
#pragma unroll
    for (int k = 0; k < 8; ++k) attnw[d * LSEQ + t + 256 * k] = vals[k] * inv;
}

// ---------------------------------------------------------------------------
// 4a. attn_out partials: block b -> d=b>>5, l-chunk c=b&31 (64 l each).
//     Each thread owns 4 h positions (t, t+256, t+512, t+768).
__global__ void attnout_partial_kernel(const float* __restrict__ enc,
                                       const float* __restrict__ attnw,
                                       float* __restrict__ part) {
    int b = blockIdx.x;                          // 64 blocks
    int d = b >> 5, c = b & 31;
    int t = threadIdx.x;
    float acc0 = 0, acc1 = 0, acc2 = 0, acc3 = 0;
    const float* aw = attnw + d * LSEQ + c * 64;
    const float* e  = enc + (size_t)(c * 64) * HDIM;
    for (int l = 0; l < 64; ++l) {
        float a = aw[l];
        const float* row = e + (size_t)l * HDIM;
        acc0 += a * row[t];
        acc1 += a * row[t + 256];
        acc2 += a * row[t + 512];
        acc3 += a * row[t + 768];
    }
    float* pp = part + (size_t)b * HDIM;
    pp[t] = acc0; pp[t + 256] = acc1; pp[t + 512] = acc2; pp[t + 768] = acc3;
}

// 4b. reduce partials over 32 chunks -> concat[d*2048 + h]
__global__ void attnout_reduce_kernel(const float* __restrict__ part,
                                      float* __restrict__ concat) {
    int idx = blockIdx.x * 256 + threadIdx.x;    // 8 blocks -> 0..2047
    int d = idx >> 10, h = idx & 1023;
    float s = 0.f;
#pragma unroll 8
    for (int c = 0; c < 32; ++c) s += part[(size_t)(d * 32 + c) * HDIM + h];
    concat[d * 2048 + h] = s;
}

// ---------------------------------------------------------------------------
// 5. logits[v] = concat . W_out[v] + b_out[v];  one wave per vocab row.
//    This reads 823 MB -> the bandwidth-dominant kernel.
__global__ void logits_kernel(const float* __restrict__ W_out,
                              const float* __restrict__ b_out,
                              const float* __restrict__ concat,
                              float* __restrict__ logits) {
    int wave = threadIdx.x >> 6, lane = threadIdx.x & 63;
    int v = blockIdx.x * 4 + wave;
    if (v >= VOCAB) return;
    const float* w = W_out + (size_t)v * 4096;
    float acc = 0.f;
#pragma unroll
    for (int p = 0; p < 16; ++p) {
        int o = p * 256 + lane * 4;
        float4 a = *(const float4*)(w + o);
        float4 b = *(const float4*)(concat + o);
        acc += a.x * b.x + a.y * b.y + a.z * b.z + a.w * b.w;
    }
    acc = wave_sum(acc);
    if (lane == 0) logits[v] = acc + b_out[v];
}

// ---------------------------------------------------------------------------
// 6a. per-block online log-sum-exp partials over logits. grid=128, block=256.
__global__ void lse_partial_kernel(const float* __restrict__ logits,
                                   float* __restrict__ pm,
                                   float* __restrict__ ps) {
    __shared__ float rm[4], rs[4];
    int tid = blockIdx.x * 256 + threadIdx.x;
    float m = -1e30f, s = 0.f;
    for (int v = tid; v < VOCAB; v += 128 * 256) lse_combine(m, s, logits[v], 1.f);
    int lane = threadIdx.x & 63, wave = threadIdx.x >> 6;
#pragma unroll
    for (int off = 32; off; off >>= 1) {
        float m2 = __shfl_down(m, off, 64);
        float s2 = __shfl_down(s, off, 64);
        lse_combine(m, s, m2, s2);
    }
    if (lane == 0) { rm[wave] = m; rs[wave] = s; }
    __syncthreads();
    if (threadIdx.x == 0) {
        float fm = rm[0], fs = rs[0];
        for (int w = 1; w < 4; ++w) lse_combine(fm, fs, rm[w], rs[w]);
        pm[blockIdx.x] = fm;
        ps[blockIdx.x] = fs;
    }
}

// 6b. combine 128 partials -> M = gmax + log(gsum). 1 block, 64 threads.
__global__ void lse_final_kernel(const float* __restrict__ pm,
                                 const float* __restrict__ ps,
                                 float* __restrict__ Mval) {
    int lane = threadIdx.x;
    float m = pm[lane], s = ps[lane];
    lse_combine(m, s, pm[lane + 64], ps[lane + 64]);
#pragma unroll
    for (int off = 32; off; off >>= 1) {
        float m2 = __shfl_down(m, off, 64);
        float s2 = __shfl_down(s, off, 64);
        lse_combine(m, s, m2, s2);
    }
    if (lane == 0) Mval[0] = m + logf(s);
}

// 6c. out[v] = logits[v] - M
__global__ void sub_kernel(const float* __restrict__ logits,
                           const float* __restrict__ Mval,
                           float* __restrict__ out) {
    int v = blockIdx.x * 256 + threadIdx.x;
    if (v < VOCAB) out[v] = logits[v] - Mval[0];
}

// ---------------------------------------------------------------------------
extern "C" void kernel_launch(void* const* d_in, const int* in_sizes, int n_in,
                              void* d_out, int out_size, void* d_ws, size_t ws_size,
                              hipStream_t stream) {
    const int*   tok    = (const int*)d_in[0];
    const float* hidden = (const float*)d_in[1];
    const float* enc    = (const float*)d_in[2];
    const float* emb    = (const float*)d_in[3];
    const float* W_ih   = (const float*)d_in[4];
    const float* W_hh   = (const float*)d_in[5];
    const float* b_ih   = (const float*)d_in[6];
    const float* b_hh   = (const float*)d_in[7];
    const float* W_out  = (const float*)d_in[8];
    const float* b_out  = (const float*)d_in[9];
    float* out = (float*)d_out;

    float* ws     = (float*)d_ws;
    float* concat = ws;              // 4096   [a0 | h0 | a1 | h1]
    float* energy = ws + 4096;       // 4096
    float* attnw  = ws + 8192;       // 4096
    float* logits = ws + 12288;      // 50304 (padded)
    float* pm     = ws + 62592;      // 128
    float* ps     = ws + 62720;      // 128
    float* Mval   = ws + 62848;      // 64 (padded)
    float* part   = ws + 62912;      // 64*1024 = 65536

    rnn_kernel<<<512, 256, 0, stream>>>(tok, hidden, emb, W_ih, W_hh, b_ih, b_hh,
                                        concat, out + VOCAB);
    energy_kernel<<<1024, 256, 0, stream>>>(enc, concat, energy);
    softmax_kernel<<<2, 256, 0, stream>>>(energy, attnw);
    attnout_partial_kernel<<<64, 256, 0, stream>>>(enc, attnw, part);
    attnout_reduce_kernel<<<8, 256, 0, stream>>>(part, concat);
    logits_kernel<<<(VOCAB + 3) / 4, 256, 0, stream>>>(W_out, b_out, concat, logits);
    lse_partial_kernel<<<128, 256, 0, stream>>>(logits, pm, ps);
    lse_final_kernel<<<1, 64, 0, stream>>>(pm, ps, Mval);
    sub_kernel<<<(VOCAB + 255) / 256, 256, 0, stream>>>(logits, Mval, out);
}